// Round 9
// baseline (18.925 us; speedup 1.0000x reference)
//
#include <hip/hip_runtime.h>

#define BATCH 2048
#define IND   256
#define OUTD  256

typedef __attribute__((ext_vector_type(8))) short bf16x8;
typedef __attribute__((ext_vector_type(4))) float f32x4;

__device__ __forceinline__ ushort f2bf(float f) {
    uint u = __builtin_bit_cast(uint, f);
    u += 0x7fffu + ((u >> 16) & 1u);          // RNE
    return (ushort)(u >> 16);
}
__device__ __forceinline__ uint pack2(float lo, float hi) {
    return (uint)f2bf(lo) | ((uint)f2bf(hi) << 16);
}

// ---------------- ws layout ----------------
#define BIASOFF (1u << 20)                 // W: [0, 1MB); bias after
#define WS_NEED ((size_t)BIASOFF + 4096)

// features for one x value: [silu, B0..B6] (c7 folded: B7 = 1 - sum -> bias)
__device__ __forceinline__ uint4 feat_pack(float xv) {
    const float u = (xv + 1.0f) * 2.5f;
    float cif = floorf(u);
    cif = fminf(fmaxf(cif, 0.0f), 4.0f);
    const int ci = (int)cif;
    const float f = u - cif, mf = 1.0f - f;
    const float f2 = f * f, f3 = f2 * f;
    const float k6 = 1.0f / 6.0f;
    const float w0 = mf * mf * mf * k6;
    const float w1 = (3.0f * f3 - 6.0f * f2 + 4.0f) * k6;
    const float w3 = f3 * k6;
    const float w2 = 1.0f - w0 - w1 - w3;
    const float sg = __fdividef(xv, 1.0f + __expf(-xv));
    const float B0 = (ci == 0) ? w0 : 0.f;
    const float B1 = (ci == 1) ? w0 : (ci == 0) ? w1 : 0.f;
    const float B2 = (ci == 2) ? w0 : (ci == 1) ? w1 : (ci == 0) ? w2 : 0.f;
    const float B3 = (ci == 3) ? w0 : (ci == 2) ? w1 : (ci == 1) ? w2 : (ci == 0) ? w3 : 0.f;
    const float B4 = (ci == 4) ? w0 : (ci == 3) ? w1 : (ci == 2) ? w2 : (ci == 1) ? w3 : 0.f;
    const float B5 = (ci == 4) ? w1 : (ci == 3) ? w2 : (ci == 2) ? w3 : 0.f;
    const float B6 = (ci == 4) ? w2 : (ci == 3) ? w3 : 0.f;
    uint4 v;
    v.x = pack2(sg, B0); v.y = pack2(B1, B2);
    v.z = pack2(B3, B4); v.w = pack2(B5, B6);
    return v;
}

// ============ kernel 1: W + bias only (tiny) ============
// blocks 0..255: W row i=bid (one pack per o). blocks 256..287: bias, 8 o's each.
__global__ __launch_bounds__(256) void kan_wb(
    const float* __restrict__ coef, const float* __restrict__ sb,
    const float* __restrict__ ss, const float* __restrict__ mask,
    uint4* __restrict__ W, float* __restrict__ bias)
{
    const int bid = blockIdx.x, tid = threadIdx.x;
    __shared__ float part[32][8];
    if (bid < 256) {
        const int io = bid * OUTD + tid;
        const float m = mask[io], b = sb[io], sp = ss[io];
        const float4* cp = reinterpret_cast<const float4*>(coef + (size_t)io * 8);
        const float4 c0 = cp[0], c1 = cp[1];
        const float wb = m * b, wsp = m * sp;
        const float c7 = c1.w;
        uint4 w;
        w.x = pack2(wb,                wsp * (c0.x - c7));
        w.y = pack2(wsp * (c0.y - c7), wsp * (c0.z - c7));
        w.z = pack2(wsp * (c0.w - c7), wsp * (c1.x - c7));
        w.w = pack2(wsp * (c1.y - c7), wsp * (c1.z - c7));
        W[io] = w;
    } else {
        const int o0 = (bid - 256) * 8;
        const int ol = tid & 7, ig = tid >> 3;        // 32 i-groups of 8
        float s = 0.f;
#pragma unroll
        for (int ii = 0; ii < 8; ++ii) {
            const int i = ig * 8 + ii;
            const int io = i * OUTD + o0 + ol;
            s += mask[io] * ss[io] * coef[(size_t)io * 8 + 7];
        }
        part[ig][ol] = s;
        __syncthreads();
        if (tid < 8) {
            float acc = 0.f;
#pragma unroll
            for (int g2 = 0; g2 < 32; ++g2) acc += part[g2][tid];
            bias[o0 + tid] = acc;
        }
    }
}

// ============ kernel 2: fused feature + GEMM ============
// 256 blocks x 512 threads (1 block/CU). Block tile 32M x 64N, full K.
// xcd = bid&7: n-tile = xcd>>1 (W/coef slice L2-resident), m-tile = (bid>>3)*2 + (xcd&1).
// 8 waves = nh(2 N-halves) x kq(4-way K-split per 32-i chunk). Wave tile 32x32 (2x2 frags).
// Per chunk of 32 i: feat (2 packs/thread) -> XOR-swizzled LDS A; B-frags register-direct
// from W (global, L2-hit), prefetched at chunk top so feat VALU hides latency.
__global__ __launch_bounds__(512, 4) void kan_fgemm(
    const float* __restrict__ x, const uint4* __restrict__ W,
    const float* __restrict__ bias, float* __restrict__ out)
{
    __shared__ float xs[32 * 256];     // 32 KB x-tile (il-fast reads: no pad needed)
    __shared__ uint4 At[32 * 32];      // 16 KB A-tile, slot ^= row&7 swizzle

    const int tid  = threadIdx.x;
    const int lane = tid & 63, wid = tid >> 6;
    const int nh = wid & 1, kq = wid >> 1;            // kq 0..3
    const int r = lane & 15, g = lane >> 4;
    const int bid = blockIdx.x;
    const int xcd = bid & 7;
    const int o0 = (xcd >> 1) * 64;
    const int b0 = ((bid >> 3) * 2 + (xcd & 1)) * 32;

    // ---- load x-tile (32 rows x 256), coalesced float4 ----
    {
        const int row = tid >> 4, c0 = (tid & 15) * 4;
#pragma unroll
        for (int q2 = 0; q2 < 4; ++q2) {
            const float4 v = *reinterpret_cast<const float4*>(
                x + (size_t)(b0 + row) * IND + c0 + q2 * 64);
            *reinterpret_cast<float4*>(xs + row * 256 + c0 + q2 * 64) = v;
        }
    }

    const int frow = tid >> 5;        // 0..15 (pass 2 adds 16)
    const int fil  = tid & 31;        // i within chunk (lane-fast: conflict-free xs reads)

    f32x4 acc[2][2] = {};
    __syncthreads();                  // xs ready

#pragma unroll
    for (int t = 0; t < 8; ++t) {
        const int i0 = t * 32;

        // ---- B-frag prefetch (register-direct, XCD-local L2) ----
        const uint4* pB = W + (size_t)(i0 + kq * 8 + g) * OUTD + o0 + nh * 32 + r;
        const bf16x8 b00 = *reinterpret_cast<const bf16x8*>(pB);
        const bf16x8 b01 = *reinterpret_cast<const bf16x8*>(pB + 16);
        const bf16x8 b10 = *reinterpret_cast<const bf16x8*>(pB + 4 * OUTD);
        const bf16x8 b11 = *reinterpret_cast<const bf16x8*>(pB + 4 * OUTD + 16);

        // ---- features into registers (hides B latency) ----
        const uint4 f0 = feat_pack(xs[frow * 256 + i0 + fil]);
        const uint4 f1 = feat_pack(xs[(frow + 16) * 256 + i0 + fil]);

        __syncthreads();              // prev chunk's MFMA reads of At done
        At[frow * 32 + (fil ^ (frow & 7))] = f0;
        At[(frow + 16) * 32 + (fil ^ ((frow + 16) & 7))] = f1;
        __syncthreads();              // At visible

        // ---- MFMA: 2 k-steps of 4 i each (kq's 8-i slice) ----
        const int s0 = kq * 8 + g;
        const int s1 = s0 + 4;
        const int ra0 = r, ra1 = 16 + r;
        const bf16x8 a00 = *reinterpret_cast<const bf16x8*>(At + ra0 * 32 + (s0 ^ (ra0 & 7)));
        const bf16x8 a10 = *reinterpret_cast<const bf16x8*>(At + ra1 * 32 + (s0 ^ (ra1 & 7)));
        const bf16x8 a01 = *reinterpret_cast<const bf16x8*>(At + ra0 * 32 + (s1 ^ (ra0 & 7)));
        const bf16x8 a11 = *reinterpret_cast<const bf16x8*>(At + ra1 * 32 + (s1 ^ (ra1 & 7)));

        acc[0][0] = __builtin_amdgcn_mfma_f32_16x16x32_bf16(a00, b00, acc[0][0], 0, 0, 0);
        acc[0][1] = __builtin_amdgcn_mfma_f32_16x16x32_bf16(a00, b01, acc[0][1], 0, 0, 0);
        acc[1][0] = __builtin_amdgcn_mfma_f32_16x16x32_bf16(a10, b00, acc[1][0], 0, 0, 0);
        acc[1][1] = __builtin_amdgcn_mfma_f32_16x16x32_bf16(a10, b01, acc[1][1], 0, 0, 0);
        acc[0][0] = __builtin_amdgcn_mfma_f32_16x16x32_bf16(a01, b10, acc[0][0], 0, 0, 0);
        acc[0][1] = __builtin_amdgcn_mfma_f32_16x16x32_bf16(a01, b11, acc[0][1], 0, 0, 0);
        acc[1][0] = __builtin_amdgcn_mfma_f32_16x16x32_bf16(a11, b10, acc[1][0], 0, 0, 0);
        acc[1][1] = __builtin_amdgcn_mfma_f32_16x16x32_bf16(a11, b11, acc[1][1], 0, 0, 0);
    }

    // ---- epilogue: 4-way kq-reduce per N-half via LDS (reuse xs), bias, store ----
    __syncthreads();
    float* red = xs;                  // 2 x 3 x 1024 floats = 24 KB
    if (kq > 0) {
        float* dst = red + (size_t)(nh * 3 + kq - 1) * 1024;
#pragma unroll
        for (int mf = 0; mf < 2; ++mf)
#pragma unroll
            for (int nf = 0; nf < 2; ++nf)
                *reinterpret_cast<f32x4*>(dst + (mf * 2 + nf) * 256 + lane * 4) = acc[mf][nf];
    }
    __syncthreads();
    if (kq == 0) {
#pragma unroll
        for (int mf = 0; mf < 2; ++mf)
#pragma unroll
            for (int nf = 0; nf < 2; ++nf) {
                f32x4 s = acc[mf][nf];
                const int sl = (mf * 2 + nf) * 256 + lane * 4;
#pragma unroll
                for (int kk = 0; kk < 3; ++kk) {
                    const f32x4 v = *reinterpret_cast<const f32x4*>(
                        red + (size_t)(nh * 3 + kk) * 1024 + sl);
                    s.x += v.x; s.y += v.y; s.z += v.z; s.w += v.w;
                }
                const int col  = o0 + nh * 32 + nf * 16 + r;
                const int row0 = b0 + mf * 16 + g * 4;
                const float bv = bias[col];
#pragma unroll
                for (int e = 0; e < 4; ++e)
                    out[(size_t)(row0 + e) * OUTD + col] = s[e] + bv;
            }
    }
}

// ============ fallback (used only if ws too small) ============
#define KPI  16
#define IPC  8
#define KC   (IPC * KPI)

__global__ __launch_bounds__(256, 2) void kan_mfma(
    const float* __restrict__ x, const float* __restrict__ coef,
    const float* __restrict__ scale_base, const float* __restrict__ scale_sp,
    const float* __restrict__ mask, float* __restrict__ out)
{
    const int tid = threadIdx.x;
    const int b0 = blockIdx.x * 32, o0 = blockIdx.y * 32;
    __shared__ uint Fa[32 * KC / 2];
    __shared__ uint Wt2[32 * KC / 2];
    for (int j = tid; j < 32 * KC / 2; j += 256) { Fa[j] = 0u; Wt2[j] = 0u; }
    const int lane = tid & 63, wid = tid >> 6;
    const int wmv = (wid >> 1) * 16, wnv = (wid & 1) * 16;
    f32x4 acc = {0.f, 0.f, 0.f, 0.f};
    const int fb = tid & 31, il = tid >> 5;
    for (int ic = 0; ic < IND / IPC; ++ic) {
        const int i = ic * IPC + il;
        __syncthreads();
        {
            const uint4 fp = feat_pack(x[(b0 + fb) * IND + i]);
            const int base = fb * (KC / 2) + il * (KPI / 2);
            const int sw = (fb & 7) << 2;
            Fa[(base + 0) ^ sw] = fp.x; Fa[(base + 1) ^ sw] = fp.y;
            Fa[(base + 2) ^ sw] = fp.z; Fa[(base + 3) ^ sw] = fp.w;
            ((ushort*)Fa)[2 * ((base + 4) ^ sw)] = 0;
        }
        {
            const int io = i * OUTD + o0 + fb;
            const float m = mask[io];
            const float wb = scale_base[io] * m, wsv = scale_sp[io] * m;
            const float4* cp = reinterpret_cast<const float4*>(coef + (size_t)io * 8);
            const float4 c0 = cp[0], c1 = cp[1];
            const float c7 = c1.w;
            const int base = fb * (KC / 2) + il * (KPI / 2);
            const int sw = (fb & 7) << 2;
            Wt2[(base + 0) ^ sw] = pack2(wb, wsv * (c0.x - c7));
            Wt2[(base + 1) ^ sw] = pack2(wsv * (c0.y - c7), wsv * (c0.z - c7));
            Wt2[(base + 2) ^ sw] = pack2(wsv * (c0.w - c7), wsv * (c1.x - c7));
            Wt2[(base + 3) ^ sw] = pack2(wsv * (c1.y - c7), wsv * (c1.z - c7));
            ((ushort*)Wt2)[2 * ((base + 4) ^ sw)] = 0;
        }
        __syncthreads();
        {
            const ushort* fs = (const ushort*)Fa;
            const ushort* wsd = (const ushort*)Wt2;
            const int ar = wmv + (lane & 15), br = wnv + (lane & 15);
            const int kg = (lane >> 4) * 8;
#pragma unroll
            for (int ksi = 0; ksi < 4; ++ksi) {
                const int ka = ksi * 32 + kg;
                const int ia = (ar * KC + ka) ^ ((ar & 7) << 3);
                const int ib = (br * KC + ka) ^ ((br & 7) << 3);
                bf16x8 a = *reinterpret_cast<const bf16x8*>(fs + ia);
                bf16x8 b = *reinterpret_cast<const bf16x8*>(wsd + ib);
                acc = __builtin_amdgcn_mfma_f32_16x16x32_bf16(a, b, acc, 0, 0, 0);
            }
        }
    }
    const int col = o0 + wnv + (lane & 15);
    const int row0 = b0 + wmv + ((lane >> 4) << 2);
    float bv = 0.f;
    for (int i = 0; i < IND; ++i) {
        const int io = i * OUTD + col;
        bv += mask[io] * scale_sp[io] * coef[(size_t)io * 8 + 7];
    }
#pragma unroll
    for (int rr = 0; rr < 4; ++rr)
        out[(size_t)(row0 + rr) * OUTD + col] = acc[rr] + bv;
}

extern "C" void kernel_launch(void* const* d_in, const int* in_sizes, int n_in,
                              void* d_out, int out_size, void* d_ws, size_t ws_size,
                              hipStream_t stream) {
    const float* x          = (const float*)d_in[0];
    const float* coef       = (const float*)d_in[2];
    const float* scale_base = (const float*)d_in[3];
    const float* scale_sp   = (const float*)d_in[4];
    const float* mask       = (const float*)d_in[5];
    float* out = (float*)d_out;

    if (ws_size >= WS_NEED) {
        uint4* W    = (uint4*)d_ws;
        float* bias = (float*)((char*)d_ws + BIASOFF);
        kan_wb<<<288, 256, 0, stream>>>(coef, scale_base, scale_sp, mask, W, bias);
        kan_fgemm<<<256, 512, 0, stream>>>(x, W, bias, out);
    } else {
        kan_mfma<<<dim3(BATCH / 32, OUTD / 32), 256, 0, stream>>>(
            x, coef, scale_base, scale_sp, mask, out);
    }
}